// Round 8
// baseline (539.145 us; speedup 1.0000x reference)
//
#include <hip/hip_runtime.h>
#include <hip/hip_bf16.h>

typedef __bf16 bf16;
typedef bf16 bf16x4 __attribute__((ext_vector_type(4)));
typedef bf16 bf16x8 __attribute__((ext_vector_type(8)));
typedef float f32x4 __attribute__((ext_vector_type(4)));

#define GLD_LDS16(gptr, lptr) \
  __builtin_amdgcn_global_load_lds((const __attribute__((address_space(1))) unsigned int*)(gptr), \
                                   (__attribute__((address_space(3))) unsigned int*)(lptr), 16, 0, 0)

// ---------------------------------------------------------------------------
// prep: fused prologue — one launch instead of four serialized small kernels.
//   blocks [0,512):      ctab[t][f] = {cos,sin}(t*invf(f)), t<4096, f<32
//   blocks [512,3584):   Wqkv fp32 (1024x3072) -> WqkvT bf16 (3072x1024)
//   blocks [3584,4608):  Wout fp32 (1024x1024) -> WoutT bf16 (1024x1024)
//   blocks [4608,12800): x fp32 -> xB bf16 (16M elems, 8/thread)
// ---------------------------------------------------------------------------
__global__ __launch_bounds__(256) void prep(const float* __restrict__ Wqkv,
                                            const float* __restrict__ Wout,
                                            const float* __restrict__ x,
                                            bf16* __restrict__ WqkvT,
                                            bf16* __restrict__ WoutT,
                                            bf16* __restrict__ xB,
                                            float2* __restrict__ ctab) {
  const int bid = blockIdx.x;
  if (bid >= 4608) {
    const size_t i = ((size_t)(bid - 4608) * 256 + threadIdx.x) * 8;
    float4 a = *(const float4*)(x + i);
    float4 b = *(const float4*)(x + i + 4);
    bf16x8 o;
    o[0] = (bf16)a.x; o[1] = (bf16)a.y; o[2] = (bf16)a.z; o[3] = (bf16)a.w;
    o[4] = (bf16)b.x; o[5] = (bf16)b.y; o[6] = (bf16)b.z; o[7] = (bf16)b.w;
    *(bf16x8*)(xB + i) = o;
    return;
  }
  if (bid < 512) {
    const int idx = bid * 256 + threadIdx.x;   // 131072 total
    const int t = idx >> 5, f = idx & 31;
    const float invf = (float)exp(-((double)f / 32.0) * log(500000.0));
    float sn, cs;
    sincosf((float)t * invf, &sn, &cs);
    ctab[idx] = make_float2(cs, sn);
    return;
  }
  __shared__ float tile[32][33];
  const float* in;
  bf16* out;
  int R, C, bx, by;
  if (bid < 3584) {
    const int t = bid - 512;
    in = Wqkv; out = WqkvT; R = 1024; C = 3072;
    bx = (t % 96) * 32; by = (t / 96) * 32;
  } else {
    const int t = bid - 3584;
    in = Wout; out = WoutT; R = 1024; C = 1024;
    bx = (t & 31) * 32; by = (t >> 5) * 32;
  }
  const int tx = threadIdx.x & 31;
  const int ty = threadIdx.x >> 5;
#pragma unroll
  for (int i = 0; i < 4; i++)
    tile[ty + i * 8][tx] = in[(size_t)(by + ty + i * 8) * C + bx + tx];
  __syncthreads();
#pragma unroll
  for (int i = 0; i < 4; i++)
    out[(size_t)(bx + ty + i * 8) * R + by + tx] = (bf16)tile[tx][ty + i * 8];
}

// ---------------------------------------------------------------------------
// 256x256 tile GEMM core, BK=64, 8 waves (512 thr). R2 structure (best
// measured) — schedule is maximal for the 128KiB 4-region ring; do not
// re-derive. K-half phasing, counted vmcnt(8), lgkmcnt(0)+sched_barrier
// before the MFMA cluster, two barriers per phase.
// ---------------------------------------------------------------------------
__device__ __forceinline__ void gemm256_core(const bf16* __restrict__ A,
                                             const bf16* __restrict__ BT,
                                             const int K, const int m0, const int n0,
                                             bf16* __restrict__ As, bf16* __restrict__ Bs,
                                             f32x4 acc[8][4]) {
  const int tid = threadIdx.x;
  const int lane = tid & 63;
  const int w = tid >> 6;
  const int wm = w >> 2, wn = w & 3;

#pragma unroll
  for (int i = 0; i < 8; i++)
#pragma unroll
    for (int j = 0; j < 4; j++) acc[i][j] = f32x4{0.f, 0.f, 0.f, 0.f};

  const int lch = (tid & 3) ^ ((tid >> 3) & 3);
  const bf16* Ag = A + (size_t)(m0 + (tid >> 2)) * K + lch * 8;
  const bf16* Bg = BT + (size_t)(n0 + (tid >> 2)) * K + lch * 8;
  const int wb = w * 512;

#define STG(kh, db, k0)                                                   \
  do {                                                                    \
    bf16* aD = As + ((db) * 2 + (kh)) * 8192 + wb;                        \
    bf16* bD = Bs + ((db) * 2 + (kh)) * 8192 + wb;                        \
    const size_t go = (size_t)(k0) + (kh) * 32;                           \
    GLD_LDS16(Ag + go, aD);                                               \
    GLD_LDS16(Ag + (size_t)128 * K + go, aD + 4096);                      \
    GLD_LDS16(Bg + go, bD);                                               \
    GLD_LDS16(Bg + (size_t)128 * K + go, bD + 4096);                      \
  } while (0)

  const int fr = lane & 15;
  const int kq = lane >> 4;
  const int frow = fr * 32 + ((kq ^ ((fr >> 1) & 3)) << 3);
  const int aro = wm * 4096;
  const int bro = wn * 2048;

#define LOADFRAGS(kh, db)                                                 \
  const bf16* Ap = As + ((db) * 2 + (kh)) * 8192 + aro + frow;            \
  const bf16* Bp = Bs + ((db) * 2 + (kh)) * 8192 + bro + frow;            \
  bf16x8 af[8], bv[4];                                                    \
  _Pragma("unroll") for (int mi = 0; mi < 8; mi++)                        \
      af[mi] = *(const bf16x8*)(Ap + mi * 512);                           \
  _Pragma("unroll") for (int ni = 0; ni < 4; ni++)                        \
      bv[ni] = *(const bf16x8*)(Bp + ni * 512);

#define MFMA32                                                            \
  __builtin_amdgcn_s_setprio(1);                                          \
  _Pragma("unroll") for (int mi = 0; mi < 8; mi++)                        \
  _Pragma("unroll") for (int ni = 0; ni < 4; ni++)                        \
      acc[mi][ni] = __builtin_amdgcn_mfma_f32_16x16x32_bf16(              \
          af[mi], bv[ni], acc[mi][ni], 0, 0, 0);                          \
  __builtin_amdgcn_s_setprio(0);

  STG(0, 0, 0);
  STG(1, 0, 0);
  if (K > 64) {
    STG(0, 1, 64);
    asm volatile("s_waitcnt vmcnt(8)" ::: "memory");
  } else {
    asm volatile("s_waitcnt vmcnt(4)" ::: "memory");
  }
  __builtin_amdgcn_s_barrier();

  const int NT = K >> 6;
  for (int kt = 0; kt < NT; ++kt) {
    const int db = kt & 1;
    // ---------------- phase A: k-slice [kt*64, kt*64+32) ----------------
    {
      LOADFRAGS(0, db);
      if (kt + 1 < NT) STG(1, db ^ 1, (kt + 1) * 64);  // khi(kt+1)
      __builtin_amdgcn_s_barrier();
      asm volatile("s_waitcnt lgkmcnt(0)" ::: "memory");
      __builtin_amdgcn_sched_barrier(0);
      MFMA32;
      if (kt + 1 < NT) asm volatile("s_waitcnt vmcnt(8)" ::: "memory");
      else             asm volatile("s_waitcnt vmcnt(0)" ::: "memory");
      __builtin_amdgcn_s_barrier();
    }
    // ---------------- phase B: k-slice [kt*64+32, kt*64+64) ----------------
    {
      LOADFRAGS(1, db);
      if (kt + 2 < NT) STG(0, db, (kt + 2) * 64);      // klo(kt+2)
      __builtin_amdgcn_s_barrier();
      asm volatile("s_waitcnt lgkmcnt(0)" ::: "memory");
      __builtin_amdgcn_sched_barrier(0);
      MFMA32;
      if (kt + 2 < NT)      asm volatile("s_waitcnt vmcnt(8)" ::: "memory");
      else if (kt + 1 < NT) asm volatile("s_waitcnt vmcnt(4)" ::: "memory");
      __builtin_amdgcn_s_barrier();
    }
  }
#undef STG
#undef LOADFRAGS
#undef MFMA32
}

// bijective XCD swizzle (nwg % 8 == 0 for all our grids)
__device__ __forceinline__ void xcd_tile(int& m0, int& n0) {
  const int gx = gridDim.x;
  const int nwg = gx * gridDim.y;
  const int orig = blockIdx.y * gx + blockIdx.x;
  const int cpx = nwg >> 3;
  const int swb = (orig & 7) * cpx + (orig >> 3);
  m0 = (swb / gx) * 256;
  n0 = (swb % gx) * 256;
}

// ---------------------------------------------------------------------------
// QKV GEMM with fused rope(table)+scale+elu+1 epilogue.  (R5-proven.)
// x[16384,1024] bf16 @ WqkvT[3072,1024] bf16 -> head-major qf/kf/vf
// [bh=64][t=4096][d=64]. A wave's 64-col span == one head.
// ---------------------------------------------------------------------------
__global__ __launch_bounds__(512, 2) void gemm_qkv_fused(const bf16* __restrict__ A,
                                                         const bf16* __restrict__ BT,
                                                         const float2* __restrict__ ctab,
                                                         bf16* __restrict__ qfB,
                                                         bf16* __restrict__ kfB,
                                                         bf16* __restrict__ vfB) {
  __shared__ __attribute__((aligned(16))) bf16 As[32768];
  __shared__ __attribute__((aligned(16))) bf16 Bs[32768];
  const int K = 1024;
  int m0, n0;
  xcd_tile(m0, n0);

  f32x4 acc[8][4];
  gemm256_core(A, BT, K, m0, n0, As, Bs, acc);

  const int lane = threadIdx.x & 63;
  const int w = threadIdx.x >> 6;
  const int wm = w >> 2, wn = w & 3;
  const int fr15 = lane & 15;
  const int cb = n0 + wn * 64;            // wave-uniform column block (one head)
  const int p = cb >> 10;                 // 0=q, 1=k, 2=v
  const int hh = (cb & 1023) >> 6;
  const int row00 = m0 + wm * 128 + ((lane >> 4) << 2);
  const int b = row00 >> 12;              // wave-uniform (256-row blocks never straddle batch)
  const size_t base0 = ((size_t)(b * 16 + hh)) * 4096 * 64;

  if (p == 2) {
#pragma unroll
    for (int mi = 0; mi < 8; mi++)
#pragma unroll
      for (int r = 0; r < 4; r++) {
        const int tloc = (row00 + mi * 16 + r) & 4095;
        bf16* dst = vfB + base0 + (size_t)tloc * 64;
#pragma unroll
        for (int ni = 0; ni < 4; ni++) dst[fr15 + ni * 16] = (bf16)acc[mi][ni][r];
      }
  } else {
    bf16* outp = (p == 0) ? qfB : kfB;
    const float scl = (p == 0) ? 0.125f : 1.0f;
#pragma unroll
    for (int mi = 0; mi < 8; mi++)
#pragma unroll
      for (int r = 0; r < 4; r++) {
        const int tloc = (row00 + mi * 16 + r) & 4095;
        const float2* ct = ctab + tloc * 32;
        bf16* dst = outp + base0 + (size_t)tloc * 64;
#pragma unroll
        for (int ni = 0; ni < 2; ni++) {
          const float2 cs2 = ct[fr15 + ni * 16];
          const float x1 = acc[mi][ni][r], x2 = acc[mi][ni + 2][r];
          const float r1 = (x1 * cs2.x - x2 * cs2.y) * scl;
          const float r2 = (x2 * cs2.x + x1 * cs2.y) * scl;
          dst[fr15 + ni * 16] = (bf16)(r1 > 0.f ? r1 + 1.f : __expf(r1));
          dst[fr15 + ni * 16 + 32] = (bf16)(r2 > 0.f ? r2 + 1.f : __expf(r2));
        }
      }
  }
}

// ---------------------------------------------------------------------------
// Plain GEMM (final projection): C fp32 = A bf16 @ BT^T bf16.
// ---------------------------------------------------------------------------
__global__ __launch_bounds__(512, 2) void gemm_bt_f32(const bf16* __restrict__ A,
                                                      const bf16* __restrict__ BT,
                                                      float* __restrict__ C,
                                                      int N, int K) {
  __shared__ __attribute__((aligned(16))) bf16 As[32768];
  __shared__ __attribute__((aligned(16))) bf16 Bs[32768];
  int m0, n0;
  xcd_tile(m0, n0);

  f32x4 acc[8][4];
  gemm256_core(A, BT, K, m0, n0, As, Bs, acc);

  const int lane = threadIdx.x & 63;
  const int w = threadIdx.x >> 6;
  const int wm = w >> 2, wn = w & 3;
  const int col0 = n0 + wn * 64 + (lane & 15);
  const int row00 = m0 + wm * 128 + ((lane >> 4) << 2);
#pragma unroll
  for (int mi = 0; mi < 8; mi++)
#pragma unroll
    for (int ni = 0; ni < 4; ni++)
#pragma unroll
      for (int r = 0; r < 4; r++)
        C[(size_t)(row00 + mi * 16 + r) * N + col0 + ni * 16] = acc[mi][ni][r];
}

// ---------------------------------------------------------------------------
// attn_kv: per (b,h) kv[64][64] = sum_t kf[t] (x) v[t], ksum[64] = sum_t kf[t].
// Compute body identical to R2/R5-proven version. ONLY change vs R5: the
// epilogue transposes acc through LDS (reusing the staging buffer) so the
// global atomicAdds are LINE-COALESCED — thread tid owns row tid>>2, 16
// consecutive floats = one 64B line; a wave covers 16 contiguous rows (4KB).
// (R5's direct epilogue scattered 16B RMWs across 64 lines per wave.)
// ---------------------------------------------------------------------------
__global__ __launch_bounds__(256) void attn_kv(const bf16* __restrict__ kfB,
                                               const bf16* __restrict__ vfB,
                                               float* __restrict__ kvg,
                                               float* __restrict__ ksumg) {
  const int bh = blockIdx.x;
  const int t0 = blockIdx.y * 256;
  __shared__ __attribute__((aligned(16))) float sh[4352];  // kfs|vfs; reused as kv scratch
  float (*kfs)[68] = (float(*)[68])sh;
  float (*vfs)[68] = (float(*)[68])(sh + 2176);
  const int tid = threadIdx.x;
  const int dq = tid & 15, g = tid >> 4;
  const int tl = tid >> 3, ch = (tid & 7) * 8;

  f32x4 acc[4];
#pragma unroll
  for (int r = 0; r < 4; r++) acc[r] = f32x4{0.f, 0.f, 0.f, 0.f};
  float ksa[4] = {0.f, 0.f, 0.f, 0.f};

  for (int sc = 0; sc < 8; sc++) {
    const size_t rowb = ((size_t)bh * 4096 + t0 + sc * 32 + tl) * 64 + ch;
    bf16x8 k8 = *(const bf16x8*)(kfB + rowb);
    bf16x8 v8 = *(const bf16x8*)(vfB + rowb);
    f32x4 ka, kb, va, vb;
#pragma unroll
    for (int j = 0; j < 4; j++) {
      ka[j] = (float)k8[j]; kb[j] = (float)k8[j + 4];
      va[j] = (float)v8[j]; vb[j] = (float)v8[j + 4];
    }
    *(f32x4*)&kfs[tl][ch] = ka;
    *(f32x4*)&kfs[tl][ch + 4] = kb;
    *(f32x4*)&vfs[tl][ch] = va;
    *(f32x4*)&vfs[tl][ch + 4] = vb;
    __syncthreads();

#pragma unroll 8
    for (int t = 0; t < 32; t++) {
      f32x4 kq = *(const f32x4*)&kfs[t][dq * 4];
      f32x4 vq = *(const f32x4*)&vfs[t][g * 4];
#pragma unroll
      for (int r = 0; r < 4; r++) {
#pragma unroll
        for (int c = 0; c < 4; c++) acc[r][c] += kq[r] * vq[c];
      }
      if (g == 0) {
#pragma unroll
        for (int r = 0; r < 4; r++) ksa[r] += kq[r];
      }
    }
    __syncthreads();
  }

  // ---- epilogue: LDS transpose -> line-coalesced global atomics ----
  // (sc-loop ended on __syncthreads, so sh is free to overwrite)
  float* kvs = sh;                         // [64][65] = 4160 floats <= 4352
#pragma unroll
  for (int r = 0; r < 4; r++)
    *(f32x4*)&kvs[(dq * 4 + r) * 65 + g * 4] = acc[r];
  __syncthreads();
  {
    const int row = tid >> 2, c0 = (tid & 3) * 16;
    float* dstg = kvg + (size_t)bh * 4096 + row * 64 + c0;
    const float* srcl = kvs + row * 65 + c0;
#pragma unroll
    for (int j = 0; j < 16; j++) atomicAdd(dstg + j, srcl[j]);
  }
  if (g == 0) {
#pragma unroll
    for (int r = 0; r < 4; r++) atomicAdd(&ksumg[bh * 64 + dq * 4 + r], ksa[r]);
  }
}

// ---------------------------------------------------------------------------
// attn_out: out[t] = (qf[t] @ kv) / max(qf[t]·ksum, 1e-6).  (R2/R5-proven.)
// ---------------------------------------------------------------------------
__global__ __launch_bounds__(256) void attn_out(const bf16* __restrict__ qfB,
                                                const float* __restrict__ kvg,
                                                const float* __restrict__ ksumg,
                                                bf16* __restrict__ attn) {
  const int bh = blockIdx.y;
  const int b = bh >> 4, h = bh & 15;
  const int t0 = blockIdx.x * 64;
  __shared__ __attribute__((aligned(16))) float qf[64][68];
  __shared__ __attribute__((aligned(16))) float kvs[64][64];
  __shared__ __attribute__((aligned(16))) float ksums[64];
  const int tid = threadIdx.x;

#pragma unroll
  for (int j = 0; j < 2; j++) {
    int chunk = tid + 256 * j;
    int tl = chunk >> 3, col = (chunk & 7) * 8;
    bf16x8 r = *(const bf16x8*)(qfB + ((size_t)bh * 4096 + t0 + tl) * 64 + col);
    f32x4 a, bb;
#pragma unroll
    for (int q = 0; q < 4; q++) { a[q] = (float)r[q]; bb[q] = (float)r[q + 4]; }
    *(f32x4*)&qf[tl][col] = a;
    *(f32x4*)&qf[tl][col + 4] = bb;
  }
#pragma unroll
  for (int j = 0; j < 4; j++) {
    int idx = tid + 256 * j;
    *(float4*)&kvs[idx >> 4][(idx & 15) * 4] = *(const float4*)&kvg[(size_t)bh * 4096 + idx * 4];
  }
  if (tid < 64) ksums[tid] = ksumg[bh * 64 + tid];
  __syncthreads();

  const int tr = tid >> 4, cc = tid & 15;
  f32x4 acc[4];
#pragma unroll
  for (int r = 0; r < 4; r++) acc[r] = f32x4{0.f, 0.f, 0.f, 0.f};
  f32x4 dn = f32x4{0.f, 0.f, 0.f, 0.f};

  for (int d2 = 0; d2 < 64; d2++) {
    f32x4 kv4 = *(const f32x4*)&kvs[d2][cc * 4];
    float ks = ksums[d2];
#pragma unroll
    for (int r = 0; r < 4; r++) {
      float qv = qf[tr * 4 + r][d2];
      acc[r] += qv * kv4;
      dn[r] += qv * ks;
    }
  }

#pragma unroll
  for (int r = 0; r < 4; r++) {
    const float rdn = 1.f / fmaxf(dn[r], 1e-6f);
    bf16x4 o;
#pragma unroll
    for (int c = 0; c < 4; c++) o[c] = (bf16)(acc[r][c] * rdn);
    *(bf16x4*)(attn + ((size_t)(b * 4096) + t0 + tr * 4 + r) * 1024 + h * 64 + cc * 4) = o;
  }
}

// ---------------------------------------------------------------------------
// Workspace layout (bytes):
//   kvg   f32  [64*64*64]     @ 0          size   1048576
//   ksumg f32  [64*64]        @ 1048576    size     16384
//   WqkvT bf16 [3072,1024]    @ 1064960    size   6291456
//   WoutT bf16 [1024,1024]    @ 7356416    size   2097152
//   attn  bf16 [16384,1024]   @ 9453568    size  33554432
//     (first 1 MiB doubles as ctab float2[4096][32])
//   qfB   bf16 [64,4096,64]   @ 43008000   size  33554432
//   kfB   bf16 [64,4096,64]   @ 76562432   size  33554432
//   vfB   bf16 [64,4096,64]   @ 110116864  size  33554432
//   xB    bf16 [16384,1024]   @ 143671296  size  33554432
//   total 177225728 (~169 MiB)
// ---------------------------------------------------------------------------
extern "C" void kernel_launch(void* const* d_in, const int* in_sizes, int n_in,
                              void* d_out, int out_size, void* d_ws, size_t ws_size,
                              hipStream_t stream) {
  if (ws_size < 177225728ULL) return;

  const float* x = (const float*)d_in[0];
  const float* Wqkv = (const float*)d_in[1];
  const float* Wout = (const float*)d_in[2];
  float* out = (float*)d_out;
  char* ws = (char*)d_ws;

  float* kvg = (float*)(ws);
  float* ksumg = (float*)(ws + 1048576);
  bf16* WqkvT = (bf16*)(ws + 1064960);
  bf16* WoutT = (bf16*)(ws + 7356416);
  bf16* attn = (bf16*)(ws + 9453568);
  float2* ctab = (float2*)(ws + 9453568);
  bf16* qfB = (bf16*)(ws + 43008000);
  bf16* kfB = (bf16*)(ws + 76562432);
  bf16* vfB = (bf16*)(ws + 110116864);
  bf16* xB = (bf16*)(ws + 143671296);

  hipMemsetAsync(ws, 0, 1048576 + 16384, stream);

  // fused prologue: rope table + both weight transposes + x fp32->bf16
  prep<<<12800, 256, 0, stream>>>(Wqkv, Wout, x, WqkvT, WoutT, xB, ctab);

  // qkv = x @ W_qkv with fused rope/scale/elu+1 -> head-major qf/kf/vf
  gemm_qkv_fused<<<dim3(3072 / 256, 16384 / 256), 512, 0, stream>>>(xB, WqkvT, ctab, qfB, kfB, vfB);

  // linear attention core
  attn_kv<<<dim3(64, 16), 256, 0, stream>>>(kfB, vfB, kvg, ksumg);
  attn_out<<<dim3(64, 64), 256, 0, stream>>>(qfB, kvg, ksumg, attn);

  // y = attn @ W_out -> fp32 d_out
  gemm_bt_f32<<<dim3(1024 / 256, 16384 / 256), 512, 0, stream>>>(attn, WoutT, out, 1024, 1024);
}

// Round 9
// 373.432 us; speedup vs baseline: 1.4438x; 1.4438x over previous
//
#include <hip/hip_runtime.h>
#include <hip/hip_bf16.h>

typedef __bf16 bf16;
typedef bf16 bf16x4 __attribute__((ext_vector_type(4)));
typedef bf16 bf16x8 __attribute__((ext_vector_type(8)));
typedef float f32x4 __attribute__((ext_vector_type(4)));

#define GLD_LDS16(gptr, lptr) \
  __builtin_amdgcn_global_load_lds((const __attribute__((address_space(1))) unsigned int*)(gptr), \
                                   (__attribute__((address_space(3))) unsigned int*)(lptr), 16, 0, 0)

// ---------------------------------------------------------------------------
// prep: fused prologue — one launch instead of four serialized small kernels.
//   blocks [0,512):      ctab[t][f] = {cos,sin}(t*invf(f)), t<4096, f<32
//   blocks [512,3584):   Wqkv fp32 (1024x3072) -> WqkvT bf16 (3072x1024)
//   blocks [3584,4608):  Wout fp32 (1024x1024) -> WoutT bf16 (1024x1024)
//   blocks [4608,12800): x fp32 -> xB bf16 (16M elems, 8/thread)
// ---------------------------------------------------------------------------
__global__ __launch_bounds__(256) void prep(const float* __restrict__ Wqkv,
                                            const float* __restrict__ Wout,
                                            const float* __restrict__ x,
                                            bf16* __restrict__ WqkvT,
                                            bf16* __restrict__ WoutT,
                                            bf16* __restrict__ xB,
                                            float2* __restrict__ ctab) {
  const int bid = blockIdx.x;
  if (bid >= 4608) {
    const size_t i = ((size_t)(bid - 4608) * 256 + threadIdx.x) * 8;
    float4 a = *(const float4*)(x + i);
    float4 b = *(const float4*)(x + i + 4);
    bf16x8 o;
    o[0] = (bf16)a.x; o[1] = (bf16)a.y; o[2] = (bf16)a.z; o[3] = (bf16)a.w;
    o[4] = (bf16)b.x; o[5] = (bf16)b.y; o[6] = (bf16)b.z; o[7] = (bf16)b.w;
    *(bf16x8*)(xB + i) = o;
    return;
  }
  if (bid < 512) {
    const int idx = bid * 256 + threadIdx.x;   // 131072 total
    const int t = idx >> 5, f = idx & 31;
    const float invf = (float)exp(-((double)f / 32.0) * log(500000.0));
    float sn, cs;
    sincosf((float)t * invf, &sn, &cs);
    ctab[idx] = make_float2(cs, sn);
    return;
  }
  __shared__ float tile[32][33];
  const float* in;
  bf16* out;
  int R, C, bx, by;
  if (bid < 3584) {
    const int t = bid - 512;
    in = Wqkv; out = WqkvT; R = 1024; C = 3072;
    bx = (t % 96) * 32; by = (t / 96) * 32;
  } else {
    const int t = bid - 3584;
    in = Wout; out = WoutT; R = 1024; C = 1024;
    bx = (t & 31) * 32; by = (t >> 5) * 32;
  }
  const int tx = threadIdx.x & 31;
  const int ty = threadIdx.x >> 5;
#pragma unroll
  for (int i = 0; i < 4; i++)
    tile[ty + i * 8][tx] = in[(size_t)(by + ty + i * 8) * C + bx + tx];
  __syncthreads();
#pragma unroll
  for (int i = 0; i < 4; i++)
    out[(size_t)(bx + ty + i * 8) * R + by + tx] = (bf16)tile[tx][ty + i * 8];
}

// ---------------------------------------------------------------------------
// 256x256 tile GEMM core, BK=64, 8 waves (512 thr). R2 structure (best
// measured) — schedule is maximal for the 128KiB 4-region ring; do not
// re-derive. K-half phasing, counted vmcnt(8), lgkmcnt(0)+sched_barrier
// before the MFMA cluster, two barriers per phase.
// ---------------------------------------------------------------------------
__device__ __forceinline__ void gemm256_core(const bf16* __restrict__ A,
                                             const bf16* __restrict__ BT,
                                             const int K, const int m0, const int n0,
                                             bf16* __restrict__ As, bf16* __restrict__ Bs,
                                             f32x4 acc[8][4]) {
  const int tid = threadIdx.x;
  const int lane = tid & 63;
  const int w = tid >> 6;
  const int wm = w >> 2, wn = w & 3;

#pragma unroll
  for (int i = 0; i < 8; i++)
#pragma unroll
    for (int j = 0; j < 4; j++) acc[i][j] = f32x4{0.f, 0.f, 0.f, 0.f};

  const int lch = (tid & 3) ^ ((tid >> 3) & 3);
  const bf16* Ag = A + (size_t)(m0 + (tid >> 2)) * K + lch * 8;
  const bf16* Bg = BT + (size_t)(n0 + (tid >> 2)) * K + lch * 8;
  const int wb = w * 512;

#define STG(kh, db, k0)                                                   \
  do {                                                                    \
    bf16* aD = As + ((db) * 2 + (kh)) * 8192 + wb;                        \
    bf16* bD = Bs + ((db) * 2 + (kh)) * 8192 + wb;                        \
    const size_t go = (size_t)(k0) + (kh) * 32;                           \
    GLD_LDS16(Ag + go, aD);                                               \
    GLD_LDS16(Ag + (size_t)128 * K + go, aD + 4096);                      \
    GLD_LDS16(Bg + go, bD);                                               \
    GLD_LDS16(Bg + (size_t)128 * K + go, bD + 4096);                      \
  } while (0)

  const int fr = lane & 15;
  const int kq = lane >> 4;
  const int frow = fr * 32 + ((kq ^ ((fr >> 1) & 3)) << 3);
  const int aro = wm * 4096;
  const int bro = wn * 2048;

#define LOADFRAGS(kh, db)                                                 \
  const bf16* Ap = As + ((db) * 2 + (kh)) * 8192 + aro + frow;            \
  const bf16* Bp = Bs + ((db) * 2 + (kh)) * 8192 + bro + frow;            \
  bf16x8 af[8], bv[4];                                                    \
  _Pragma("unroll") for (int mi = 0; mi < 8; mi++)                        \
      af[mi] = *(const bf16x8*)(Ap + mi * 512);                           \
  _Pragma("unroll") for (int ni = 0; ni < 4; ni++)                        \
      bv[ni] = *(const bf16x8*)(Bp + ni * 512);

#define MFMA32                                                            \
  __builtin_amdgcn_s_setprio(1);                                          \
  _Pragma("unroll") for (int mi = 0; mi < 8; mi++)                        \
  _Pragma("unroll") for (int ni = 0; ni < 4; ni++)                        \
      acc[mi][ni] = __builtin_amdgcn_mfma_f32_16x16x32_bf16(              \
          af[mi], bv[ni], acc[mi][ni], 0, 0, 0);                          \
  __builtin_amdgcn_s_setprio(0);

  STG(0, 0, 0);
  STG(1, 0, 0);
  if (K > 64) {
    STG(0, 1, 64);
    asm volatile("s_waitcnt vmcnt(8)" ::: "memory");
  } else {
    asm volatile("s_waitcnt vmcnt(4)" ::: "memory");
  }
  __builtin_amdgcn_s_barrier();

  const int NT = K >> 6;
  for (int kt = 0; kt < NT; ++kt) {
    const int db = kt & 1;
    // ---------------- phase A: k-slice [kt*64, kt*64+32) ----------------
    {
      LOADFRAGS(0, db);
      if (kt + 1 < NT) STG(1, db ^ 1, (kt + 1) * 64);  // khi(kt+1)
      __builtin_amdgcn_s_barrier();
      asm volatile("s_waitcnt lgkmcnt(0)" ::: "memory");
      __builtin_amdgcn_sched_barrier(0);
      MFMA32;
      if (kt + 1 < NT) asm volatile("s_waitcnt vmcnt(8)" ::: "memory");
      else             asm volatile("s_waitcnt vmcnt(0)" ::: "memory");
      __builtin_amdgcn_s_barrier();
    }
    // ---------------- phase B: k-slice [kt*64+32, kt*64+64) ----------------
    {
      LOADFRAGS(1, db);
      if (kt + 2 < NT) STG(0, db, (kt + 2) * 64);      // klo(kt+2)
      __builtin_amdgcn_s_barrier();
      asm volatile("s_waitcnt lgkmcnt(0)" ::: "memory");
      __builtin_amdgcn_sched_barrier(0);
      MFMA32;
      if (kt + 2 < NT)      asm volatile("s_waitcnt vmcnt(8)" ::: "memory");
      else if (kt + 1 < NT) asm volatile("s_waitcnt vmcnt(4)" ::: "memory");
      __builtin_amdgcn_s_barrier();
    }
  }
#undef STG
#undef LOADFRAGS
#undef MFMA32
}

// bijective XCD swizzle (nwg % 8 == 0 for all our grids)
__device__ __forceinline__ void xcd_tile(int& m0, int& n0) {
  const int gx = gridDim.x;
  const int nwg = gx * gridDim.y;
  const int orig = blockIdx.y * gx + blockIdx.x;
  const int cpx = nwg >> 3;
  const int swb = (orig & 7) * cpx + (orig >> 3);
  m0 = (swb / gx) * 256;
  n0 = (swb % gx) * 256;
}

// ---------------------------------------------------------------------------
// QKV GEMM with fused rope(table)+scale+elu+1 epilogue.  (R5-proven.)
// x[16384,1024] bf16 @ WqkvT[3072,1024] bf16 -> head-major qf/kf/vf
// [bh=64][t=4096][d=64]. A wave's 64-col span == one head.
// ---------------------------------------------------------------------------
__global__ __launch_bounds__(512, 2) void gemm_qkv_fused(const bf16* __restrict__ A,
                                                         const bf16* __restrict__ BT,
                                                         const float2* __restrict__ ctab,
                                                         bf16* __restrict__ qfB,
                                                         bf16* __restrict__ kfB,
                                                         bf16* __restrict__ vfB) {
  __shared__ __attribute__((aligned(16))) bf16 As[32768];
  __shared__ __attribute__((aligned(16))) bf16 Bs[32768];
  const int K = 1024;
  int m0, n0;
  xcd_tile(m0, n0);

  f32x4 acc[8][4];
  gemm256_core(A, BT, K, m0, n0, As, Bs, acc);

  const int lane = threadIdx.x & 63;
  const int w = threadIdx.x >> 6;
  const int wm = w >> 2, wn = w & 3;
  const int fr15 = lane & 15;
  const int cb = n0 + wn * 64;            // wave-uniform column block (one head)
  const int p = cb >> 10;                 // 0=q, 1=k, 2=v
  const int hh = (cb & 1023) >> 6;
  const int row00 = m0 + wm * 128 + ((lane >> 4) << 2);
  const int b = row00 >> 12;              // wave-uniform (256-row blocks never straddle batch)
  const size_t base0 = ((size_t)(b * 16 + hh)) * 4096 * 64;

  if (p == 2) {
#pragma unroll
    for (int mi = 0; mi < 8; mi++)
#pragma unroll
      for (int r = 0; r < 4; r++) {
        const int tloc = (row00 + mi * 16 + r) & 4095;
        bf16* dst = vfB + base0 + (size_t)tloc * 64;
#pragma unroll
        for (int ni = 0; ni < 4; ni++) dst[fr15 + ni * 16] = (bf16)acc[mi][ni][r];
      }
  } else {
    bf16* outp = (p == 0) ? qfB : kfB;
    const float scl = (p == 0) ? 0.125f : 1.0f;
#pragma unroll
    for (int mi = 0; mi < 8; mi++)
#pragma unroll
      for (int r = 0; r < 4; r++) {
        const int tloc = (row00 + mi * 16 + r) & 4095;
        const float2* ct = ctab + tloc * 32;
        bf16* dst = outp + base0 + (size_t)tloc * 64;
#pragma unroll
        for (int ni = 0; ni < 2; ni++) {
          const float2 cs2 = ct[fr15 + ni * 16];
          const float x1 = acc[mi][ni][r], x2 = acc[mi][ni + 2][r];
          const float r1 = (x1 * cs2.x - x2 * cs2.y) * scl;
          const float r2 = (x2 * cs2.x + x1 * cs2.y) * scl;
          dst[fr15 + ni * 16] = (bf16)(r1 > 0.f ? r1 + 1.f : __expf(r1));
          dst[fr15 + ni * 16 + 32] = (bf16)(r2 > 0.f ? r2 + 1.f : __expf(r2));
        }
      }
  }
}

// ---------------------------------------------------------------------------
// Plain GEMM (final projection): C fp32 = A bf16 @ BT^T bf16.
// ---------------------------------------------------------------------------
__global__ __launch_bounds__(512, 2) void gemm_bt_f32(const bf16* __restrict__ A,
                                                      const bf16* __restrict__ BT,
                                                      float* __restrict__ C,
                                                      int N, int K) {
  __shared__ __attribute__((aligned(16))) bf16 As[32768];
  __shared__ __attribute__((aligned(16))) bf16 Bs[32768];
  int m0, n0;
  xcd_tile(m0, n0);

  f32x4 acc[8][4];
  gemm256_core(A, BT, K, m0, n0, As, Bs, acc);

  const int lane = threadIdx.x & 63;
  const int w = threadIdx.x >> 6;
  const int wm = w >> 2, wn = w & 3;
  const int col0 = n0 + wn * 64 + (lane & 15);
  const int row00 = m0 + wm * 128 + ((lane >> 4) << 2);
#pragma unroll
  for (int mi = 0; mi < 8; mi++)
#pragma unroll
    for (int ni = 0; ni < 4; ni++)
#pragma unroll
      for (int r = 0; r < 4; r++)
        C[(size_t)(row00 + mi * 16 + r) * N + col0 + ni * 16] = acc[mi][ni][r];
}

// ---------------------------------------------------------------------------
// attn_kv: per (b,h) kv[64][64] = sum_t kf[t] (x) v[t], ksum[64] = sum_t kf[t].
// R2/R5-proven version — declared 2D LDS arrays (no pointer-cast aliasing;
// R8's flat-array reuse triggered a VGPR-28 scratch-spill pathology) and
// direct per-thread global atomics.
// ---------------------------------------------------------------------------
__global__ __launch_bounds__(256) void attn_kv(const bf16* __restrict__ kfB,
                                               const bf16* __restrict__ vfB,
                                               float* __restrict__ kvg,
                                               float* __restrict__ ksumg) {
  const int bh = blockIdx.x;
  const int t0 = blockIdx.y * 256;
  __shared__ __attribute__((aligned(16))) float kfs[32][68];
  __shared__ __attribute__((aligned(16))) float vfs[32][68];
  const int tid = threadIdx.x;
  const int dq = tid & 15, g = tid >> 4;
  const int tl = tid >> 3, ch = (tid & 7) * 8;

  f32x4 acc[4];
#pragma unroll
  for (int r = 0; r < 4; r++) acc[r] = f32x4{0.f, 0.f, 0.f, 0.f};
  float ksa[4] = {0.f, 0.f, 0.f, 0.f};

  for (int sc = 0; sc < 8; sc++) {
    const size_t rowb = ((size_t)bh * 4096 + t0 + sc * 32 + tl) * 64 + ch;
    bf16x8 k8 = *(const bf16x8*)(kfB + rowb);
    bf16x8 v8 = *(const bf16x8*)(vfB + rowb);
    f32x4 ka, kb, va, vb;
#pragma unroll
    for (int j = 0; j < 4; j++) {
      ka[j] = (float)k8[j]; kb[j] = (float)k8[j + 4];
      va[j] = (float)v8[j]; vb[j] = (float)v8[j + 4];
    }
    *(f32x4*)&kfs[tl][ch] = ka;
    *(f32x4*)&kfs[tl][ch + 4] = kb;
    *(f32x4*)&vfs[tl][ch] = va;
    *(f32x4*)&vfs[tl][ch + 4] = vb;
    __syncthreads();

#pragma unroll 8
    for (int t = 0; t < 32; t++) {
      f32x4 kq = *(const f32x4*)&kfs[t][dq * 4];
      f32x4 vq = *(const f32x4*)&vfs[t][g * 4];
#pragma unroll
      for (int r = 0; r < 4; r++) {
#pragma unroll
        for (int c = 0; c < 4; c++) acc[r][c] += kq[r] * vq[c];
      }
      if (g == 0) {
#pragma unroll
        for (int r = 0; r < 4; r++) ksa[r] += kq[r];
      }
    }
    __syncthreads();
  }

#pragma unroll
  for (int r = 0; r < 4; r++)
#pragma unroll
    for (int c = 0; c < 4; c++)
      atomicAdd(&kvg[(size_t)bh * 4096 + (dq * 4 + r) * 64 + g * 4 + c], acc[r][c]);
  if (g == 0) {
#pragma unroll
    for (int r = 0; r < 4; r++) atomicAdd(&ksumg[bh * 64 + dq * 4 + r], ksa[r]);
  }
}

// ---------------------------------------------------------------------------
// attn_out: out[t] = (qf[t] @ kv) / max(qf[t]·ksum, 1e-6).  (R2/R5-proven.)
// ---------------------------------------------------------------------------
__global__ __launch_bounds__(256) void attn_out(const bf16* __restrict__ qfB,
                                                const float* __restrict__ kvg,
                                                const float* __restrict__ ksumg,
                                                bf16* __restrict__ attn) {
  const int bh = blockIdx.y;
  const int b = bh >> 4, h = bh & 15;
  const int t0 = blockIdx.x * 64;
  __shared__ __attribute__((aligned(16))) float qf[64][68];
  __shared__ __attribute__((aligned(16))) float kvs[64][64];
  __shared__ __attribute__((aligned(16))) float ksums[64];
  const int tid = threadIdx.x;

#pragma unroll
  for (int j = 0; j < 2; j++) {
    int chunk = tid + 256 * j;
    int tl = chunk >> 3, col = (chunk & 7) * 8;
    bf16x8 r = *(const bf16x8*)(qfB + ((size_t)bh * 4096 + t0 + tl) * 64 + col);
    f32x4 a, bb;
#pragma unroll
    for (int q = 0; q < 4; q++) { a[q] = (float)r[q]; bb[q] = (float)r[q + 4]; }
    *(f32x4*)&qf[tl][col] = a;
    *(f32x4*)&qf[tl][col + 4] = bb;
  }
#pragma unroll
  for (int j = 0; j < 4; j++) {
    int idx = tid + 256 * j;
    *(float4*)&kvs[idx >> 4][(idx & 15) * 4] = *(const float4*)&kvg[(size_t)bh * 4096 + idx * 4];
  }
  if (tid < 64) ksums[tid] = ksumg[bh * 64 + tid];
  __syncthreads();

  const int tr = tid >> 4, cc = tid & 15;
  f32x4 acc[4];
#pragma unroll
  for (int r = 0; r < 4; r++) acc[r] = f32x4{0.f, 0.f, 0.f, 0.f};
  f32x4 dn = f32x4{0.f, 0.f, 0.f, 0.f};

  for (int d2 = 0; d2 < 64; d2++) {
    f32x4 kv4 = *(const f32x4*)&kvs[d2][cc * 4];
    float ks = ksums[d2];
#pragma unroll
    for (int r = 0; r < 4; r++) {
      float qv = qf[tr * 4 + r][d2];
      acc[r] += qv * kv4;
      dn[r] += qv * ks;
    }
  }

#pragma unroll
  for (int r = 0; r < 4; r++) {
    const float rdn = 1.f / fmaxf(dn[r], 1e-6f);
    bf16x4 o;
#pragma unroll
    for (int c = 0; c < 4; c++) o[c] = (bf16)(acc[r][c] * rdn);
    *(bf16x4*)(attn + ((size_t)(b * 4096) + t0 + tr * 4 + r) * 1024 + h * 64 + cc * 4) = o;
  }
}

// ---------------------------------------------------------------------------
// Workspace layout (bytes):
//   kvg   f32  [64*64*64]     @ 0          size   1048576
//   ksumg f32  [64*64]        @ 1048576    size     16384
//   WqkvT bf16 [3072,1024]    @ 1064960    size   6291456
//   WoutT bf16 [1024,1024]    @ 7356416    size   2097152
//   attn  bf16 [16384,1024]   @ 9453568    size  33554432
//     (first 1 MiB doubles as ctab float2[4096][32])
//   qfB   bf16 [64,4096,64]   @ 43008000   size  33554432
//   kfB   bf16 [64,4096,64]   @ 76562432   size  33554432
//   vfB   bf16 [64,4096,64]   @ 110116864  size  33554432
//   xB    bf16 [16384,1024]   @ 143671296  size  33554432
//   total 177225728 (~169 MiB)
// ---------------------------------------------------------------------------
extern "C" void kernel_launch(void* const* d_in, const int* in_sizes, int n_in,
                              void* d_out, int out_size, void* d_ws, size_t ws_size,
                              hipStream_t stream) {
  if (ws_size < 177225728ULL) return;

  const float* x = (const float*)d_in[0];
  const float* Wqkv = (const float*)d_in[1];
  const float* Wout = (const float*)d_in[2];
  float* out = (float*)d_out;
  char* ws = (char*)d_ws;

  float* kvg = (float*)(ws);
  float* ksumg = (float*)(ws + 1048576);
  bf16* WqkvT = (bf16*)(ws + 1064960);
  bf16* WoutT = (bf16*)(ws + 7356416);
  bf16* attn = (bf16*)(ws + 9453568);
  float2* ctab = (float2*)(ws + 9453568);
  bf16* qfB = (bf16*)(ws + 43008000);
  bf16* kfB = (bf16*)(ws + 76562432);
  bf16* vfB = (bf16*)(ws + 110116864);
  bf16* xB = (bf16*)(ws + 143671296);

  hipMemsetAsync(ws, 0, 1048576 + 16384, stream);

  // fused prologue: rope table + both weight transposes + x fp32->bf16
  prep<<<12800, 256, 0, stream>>>(Wqkv, Wout, x, WqkvT, WoutT, xB, ctab);

  // qkv = x @ W_qkv with fused rope/scale/elu+1 -> head-major qf/kf/vf
  gemm_qkv_fused<<<dim3(3072 / 256, 16384 / 256), 512, 0, stream>>>(xB, WqkvT, ctab, qfB, kfB, vfB);

  // linear attention core
  attn_kv<<<dim3(64, 16), 256, 0, stream>>>(kfB, vfB, kvg, ksumg);
  attn_out<<<dim3(64, 64), 256, 0, stream>>>(qfB, kvg, ksumg, attn);

  // y = attn @ W_out -> fp32 d_out
  gemm_bt_f32<<<dim3(1024 / 256, 16384 / 256), 512, 0, stream>>>(attn, WoutT, out, 1024, 1024);
}